// Round 1
// baseline (137.081 us; speedup 1.0000x reference)
//
#include <hip/hip_runtime.h>

// Problem constants
#define N_PIX 4096   // 64*64 pixels
#define N_D   256    // feature dims
#define N_C   19     // classes
#define N_B   51     // bins

// ws layout (bytes)
#define OFF_LIST   0                      // int  [19][4096]  = 311296 B
#define OFF_COUNTS 311296                 // int  [19]
#define OFF_MIU    311424                 // float[19][256]   = 19456 B
#define OFF_VAR    330880                 // float[19][256]
#define OFF_ACC    350336                 // float[1]

// --- K1: bucket pixel indices by class (deterministic ballot compaction) ---
// grid = 19 blocks, 64 threads (1 wave). Block c compacts {n : label[n]==c}.
__global__ __launch_bounds__(64) void k_bucket(const int* __restrict__ label,
                                               int* __restrict__ list,
                                               int* __restrict__ counts,
                                               float* __restrict__ acc) {
    const int c = blockIdx.x;
    const int lane = threadIdx.x;
    if (c == 0 && lane == 0) *acc = 0.f;  // zero loss accumulator (ws is poisoned)
    int m = 0;
    for (int base = 0; base < N_PIX; base += 64) {
        const int lab = label[base + lane];
        const bool match = (lab == c);
        const unsigned long long mask = __ballot(match);
        const unsigned long long lt = (1ull << lane) - 1ull;  // lanes below me
        if (match) list[c * N_PIX + m + __popcll(mask & lt)] = base + lane;
        m += (int)__popcll(mask);
    }
    if (lane == 0) counts[c] = m;
}

// --- K2: per-(class,d) mean & variance over that class's pixels ---
// grid = (18, 64), block 256 = 4 waves; wave w handles d = 4*blockIdx.y + w.
__global__ __launch_bounds__(256) void k_stats(const float* __restrict__ feature,
                                               const int* __restrict__ list,
                                               const int* __restrict__ counts,
                                               float* __restrict__ miu,
                                               float* __restrict__ var) {
    const int c = blockIdx.x + 1;                 // class 0 never affects the loss
    const int d = blockIdx.y * 4 + (threadIdx.x >> 6);
    const int lane = threadIdx.x & 63;
    const int m = counts[c];
    const float* __restrict__ row = feature + d * N_PIX;  // F[:,d] is a contiguous row
    const int* __restrict__ lst = list + c * N_PIX;
    float s1 = 0.f, s2 = 0.f;
    for (int j = lane; j < m; j += 64) {
        const float f = row[lst[j]];
        s1 += f;
        s2 += f * f;
    }
#pragma unroll
    for (int off = 32; off; off >>= 1) {
        s1 += __shfl_down(s1, off);
        s2 += __shfl_down(s2, off);
    }
    if (lane == 0) {
        const float cnt = (float)(m > 0 ? m : 1);
        const float mu = s1 / cnt;
        const float v = fmaxf(s2 / cnt - mu * mu, 1e-12f);
        miu[c * N_D + d] = mu;
        var[c * N_D + d] = v;
    }
}

// --- K3: KDE accumulation + target + row-normalize + smooth-L1 partials ---
// grid = (18, 64), block 256 = 4 waves; wave = one (c,d) row, lane = bin.
// Norm factors 1/sqrt(2*pi*v) cancel after row normalization -> dropped.
__global__ __launch_bounds__(256) void k_kde(const float* __restrict__ feature,
                                             const int* __restrict__ list,
                                             const int* __restrict__ counts,
                                             const float* __restrict__ miu,
                                             const float* __restrict__ var,
                                             float* __restrict__ acc) {
    const int c = blockIdx.x + 1;
    const int d = blockIdx.y * 4 + (threadIdx.x >> 6);
    const int lane = threadIdx.x & 63;
    const int m = counts[c];
    __shared__ float blk[4];
    float part = 0.f;
    if (m > 0) {  // empty classes contribute nothing (active excludes them)
        const float mu = miu[c * N_D + d];
        const float v = var[c * N_D + d];
        const float LOG2E = 1.44269504088896340736f;
        const float as = -12.5f * LOG2E / v;   // sample: var/25 -> -0.5*25/v
        const float at = -0.5f * LOG2E / v;    // target
        // lanes >= 51: bin=1e18 makes every exp2 underflow to 0 -> no masking needed
        const float bin = (lane < N_B) ? fmaf(0.2f, (float)lane, -5.0f) : 1e18f;
        const float tt = bin - mu;
        const float targ = __builtin_amdgcn_exp2f(at * tt * tt);
        const float* __restrict__ row = feature + d * N_PIX;
        const int* __restrict__ lst = list + c * N_PIX;
        float acc_s = 0.f;
        for (int j = 0; j < m; ++j) {          // wave-uniform loads; ~215 iters avg
            const float f = row[lst[j]];
            const float t = bin - f;
            acc_s += __builtin_amdgcn_exp2f(as * t * t);
        }
        float ss = acc_s, st = targ;
#pragma unroll
        for (int off = 32; off; off >>= 1) {
            ss += __shfl_down(ss, off);
            st += __shfl_down(st, off);
        }
        ss = __shfl(ss, 0);
        st = __shfl(st, 0);
        const float hist = acc_s / fmaxf(ss, 1e-30f);
        const float tgt  = targ  / fmaxf(st, 1e-30f);
        const float diff = hist - tgt;
        const float ad = fabsf(diff);
        float sl1 = (ad < 1.f) ? 0.5f * diff * diff : ad - 0.5f;
#pragma unroll
        for (int off = 32; off; off >>= 1) sl1 += __shfl_down(sl1, off);
        part = sl1;  // valid on lane 0
    }
    if (lane == 0) blk[threadIdx.x >> 6] = part;
    __syncthreads();
    if (threadIdx.x == 0) atomicAdd(acc, blk[0] + blk[1] + blk[2] + blk[3]);
}

// --- K4: finalize loss = (sum / (D*B)) / (active_num + 1e-12) ---
__global__ __launch_bounds__(64) void k_final(const int* __restrict__ counts,
                                              const float* __restrict__ acc,
                                              float* __restrict__ out) {
    if (threadIdx.x == 0) {
        int active = 0;
        for (int c = 1; c < N_C; ++c) active += (counts[c] > 0) ? 1 : 0;
        out[0] = (*acc) / (float)(N_D * N_B) / ((float)active + 1e-12f);
    }
}

extern "C" void kernel_launch(void* const* d_in, const int* in_sizes, int n_in,
                              void* d_out, int out_size, void* d_ws, size_t ws_size,
                              hipStream_t stream) {
    const float* feature = (const float*)d_in[0];   // [1,256,64,64] fp32
    const int* label = (const int*)d_in[1];         // [1,1,64,64] (harness stages ints as int32)
    float* out = (float*)d_out;                     // [0]=loss, [1..]=feature passthrough
    char* ws = (char*)d_ws;
    int* list = (int*)(ws + OFF_LIST);
    int* counts = (int*)(ws + OFF_COUNTS);
    float* miu = (float*)(ws + OFF_MIU);
    float* var = (float*)(ws + OFF_VAR);
    float* acc = (float*)(ws + OFF_ACC);

    // Output 1: feature pass-through (4 MB D2D copy, graph-capturable)
    hipMemcpyAsync(out + 1, feature, (size_t)N_PIX * N_D * sizeof(float),
                   hipMemcpyDeviceToDevice, stream);

    k_bucket<<<N_C, 64, 0, stream>>>(label, list, counts, acc);
    dim3 grid(N_C - 1, N_D / 4);
    k_stats<<<grid, 256, 0, stream>>>(feature, list, counts, miu, var);
    k_kde<<<grid, 256, 0, stream>>>(feature, list, counts, miu, var, acc);
    k_final<<<1, 64, 0, stream>>>(counts, acc, out);
}

// Round 2
// 97.177 us; speedup vs baseline: 1.4106x; 1.4106x over previous
//
#include <hip/hip_runtime.h>

// Problem constants
#define N_PIX 4096   // 64*64 pixels
#define N_D   256    // feature dims
#define N_C   19     // classes
#define N_B   51     // bins

// ws layout (bytes)
#define OFF_LIST   0                      // int  [19][4096]  = 311296 B
#define OFF_COUNTS 311296                 // int  [19]
#define OFF_ACC    311424                 // float[1]

// --- K1: bucket pixel indices by class (deterministic compaction, 4 waves) ---
// grid = 19 blocks, 256 threads. Block c compacts {n : label[n]==c} in order.
__global__ __launch_bounds__(256) void k_bucket(const int* __restrict__ label,
                                                int* __restrict__ list,
                                                int* __restrict__ counts,
                                                float* __restrict__ acc) {
    const int c = blockIdx.x;
    const int w = threadIdx.x >> 6;
    const int lane = threadIdx.x & 63;
    __shared__ int wcnt[4];
    if (c == 0 && threadIdx.x == 0) *acc = 0.f;  // zero loss accumulator (ws poisoned)

    // phase 1: count matches in my quarter (1024 pixels / wave)
    const int q0 = w * 1024;
    int cnt = 0;
    for (int base = 0; base < 1024; base += 64) {
        const bool match = (label[q0 + base + lane] == c);
        cnt += (int)__popcll(__ballot(match));
    }
    if (lane == 0) wcnt[w] = cnt;
    __syncthreads();
    int m = 0;
#pragma unroll
    for (int i = 0; i < 4; ++i) m += (i < w) ? wcnt[i] : 0;

    // phase 2: scatter indices (deterministic order)
    for (int base = 0; base < 1024; base += 64) {
        const int n = q0 + base + lane;
        const bool match = (label[n] == c);
        const unsigned long long mask = __ballot(match);
        if (match) list[c * N_PIX + m + __popcll(mask & ((1ull << lane) - 1ull))] = n;
        m += (int)__popcll(mask);
    }
    if (w == 3 && lane == 0) counts[c] = m;  // off(w3) + cnt(w3) = total
}

// --- K2 (fused stats + KDE + normalize + smooth-L1): wave = one (c,d) row ---
// grid = (18, 64), block 256 = 4 waves; lane = bin. All waves in a block share
// class c, so m is block-uniform (barriers safe). Norm factors 1/sqrt(2*pi*v)
// cancel after row normalization -> dropped.
__global__ __launch_bounds__(256) void k_main(const float* __restrict__ feature,
                                              const int* __restrict__ list,
                                              const int* __restrict__ counts,
                                              float* __restrict__ acc) {
    const int c = blockIdx.x + 1;                 // class 0 never reaches the loss
    const int w = threadIdx.x >> 6;
    const int d = blockIdx.y * 4 + w;
    const int lane = threadIdx.x & 63;
    const int m = counts[c];
    __shared__ float blk[4];
    float part = 0.f;
    if (m > 0) {
        const float* __restrict__ row = feature + d * N_PIX;  // F[:,d] contiguous
        const int* __restrict__ lst = list + c * N_PIX;

        // -- stats: mean/var via lane-parallel gather + butterfly reduce --
        float s1 = 0.f, s2 = 0.f;
        for (int j = lane; j < m; j += 64) {
            const float f = row[lst[j]];
            s1 += f;
            s2 += f * f;
        }
#pragma unroll
        for (int off = 32; off; off >>= 1) {
            s1 += __shfl_xor(s1, off);
            s2 += __shfl_xor(s2, off);
        }
        const float cnt = (float)m;
        const float mu = s1 / cnt;
        const float v = fmaxf(s2 / cnt - mu * mu, 1e-12f);

        const float LOG2E = 1.44269504088896340736f;
        const float as = -12.5f * LOG2E / v;   // sample kernel: var/25 -> -0.5*25/v
        const float at = -0.5f * LOG2E / v;    // target
        // lanes >= 51: bin=1e18 -> every exp2 arg is -inf -> contributes 0
        const float bin = (lane < N_B) ? fmaf(0.2f, (float)lane, -5.0f) : 1e18f;
        const float tt = bin - mu;
        const float targ = __builtin_amdgcn_exp2f(at * tt * tt);

        // -- KDE: parallel gather of 64 pixels, then register broadcast --
        // tail pad f=-1e18 (NOT +1e18: bin sentinel is +1e18, t would be 0):
        //   lane<51:  t ~ 1e18  -> as*t^2 = -inf -> 0
        //   lane>=51: t ~ 2e18  -> t^2 = inf     -> 0
        float acc_s = 0.f;
        for (int base = 0; base < m; base += 64) {
            const int j = base + lane;
            const float fl = (j < m) ? row[lst[j]] : -1e18f;
#pragma unroll
            for (int k = 0; k < 64; ++k) {
                const float f = __shfl(fl, k);
                const float t = f - bin;       // (f-bin)^2 == (bin-f)^2
                acc_s += __builtin_amdgcn_exp2f(as * t * t);
            }
        }

        // -- row normalize + smooth-L1 --
        float ss = acc_s, st = targ;
#pragma unroll
        for (int off = 32; off; off >>= 1) {
            ss += __shfl_xor(ss, off);
            st += __shfl_xor(st, off);
        }
        const float hist = acc_s / fmaxf(ss, 1e-30f);
        const float tgt  = targ  / fmaxf(st, 1e-30f);
        const float diff = hist - tgt;
        const float ad = fabsf(diff);
        float sl1 = (ad < 1.f) ? 0.5f * diff * diff : ad - 0.5f;
#pragma unroll
        for (int off = 32; off; off >>= 1) sl1 += __shfl_down(sl1, off);
        part = sl1;  // valid on lane 0
    }
    if (lane == 0) blk[w] = part;
    __syncthreads();  // m is block-uniform -> no divergent barrier
    if (threadIdx.x == 0) atomicAdd(acc, blk[0] + blk[1] + blk[2] + blk[3]);
}

// --- K3: finalize loss = (sum / (D*B)) / (active_num + 1e-12) ---
__global__ __launch_bounds__(64) void k_final(const int* __restrict__ counts,
                                              const float* __restrict__ acc,
                                              float* __restrict__ out) {
    if (threadIdx.x == 0) {
        int active = 0;
        for (int c = 1; c < N_C; ++c) active += (counts[c] > 0) ? 1 : 0;
        out[0] = (*acc) / (float)(N_D * N_B) / ((float)active + 1e-12f);
    }
}

extern "C" void kernel_launch(void* const* d_in, const int* in_sizes, int n_in,
                              void* d_out, int out_size, void* d_ws, size_t ws_size,
                              hipStream_t stream) {
    const float* feature = (const float*)d_in[0];   // [1,256,64,64] fp32
    const int* label = (const int*)d_in[1];         // [1,1,64,64] int32
    float* out = (float*)d_out;                     // [0]=loss, [1..]=feature passthrough
    char* ws = (char*)d_ws;
    int* list = (int*)(ws + OFF_LIST);
    int* counts = (int*)(ws + OFF_COUNTS);
    float* acc = (float*)(ws + OFF_ACC);

    // Output 1: feature pass-through (4 MB D2D copy, graph-capturable)
    hipMemcpyAsync(out + 1, feature, (size_t)N_PIX * N_D * sizeof(float),
                   hipMemcpyDeviceToDevice, stream);

    k_bucket<<<N_C, 256, 0, stream>>>(label, list, counts, acc);
    dim3 grid(N_C - 1, N_D / 4);
    k_main<<<grid, 256, 0, stream>>>(feature, list, counts, acc);
    k_final<<<1, 64, 0, stream>>>(counts, acc, out);
}